// Round 18
// baseline (1682.093 us; speedup 1.0000x reference)
//
#include <hip/hip_runtime.h>
#include <math.h>

// B=16, C_IN=256, C_OUT=256, H=W=64, K=3, NK=2
// weights: [2][256][256][3][3]; bank stride 589824 floats; per-o stride 2304.
//
// Pipeline (3 kernels):
//  1. wprep: combined+modulated+demod bf16 weights -> wq per (b,c16):
//     [tap9][oh2][mf4][lane64][e8] (36864 ush). Read DIRECTLY from L2 by conv
//     (per-lane coalesced 1KB/instr) - no LDS staging for A.
//  2. xprep: x -> bf16 xq [b][c16][rowp66][colp66][io2][e8], halo zeros, plain.
//  3. conv_fused: implicit GEMM mfma_f32_32x32x16_bf16 (9 taps = 9 MFMAs/frag).
//     Block 512 thr (8 waves, 2/SIMD) = 256 o x 4 rows x 64 px; wave = (oh,ps)
//     128o x 64px, mf4 x nf2. SPLIT accumulators (even taps->accP, odd->accQ;
//     256 AGPR) break the inter-tap MFMA dependency chain; A-fragments loaded
//     L2-direct with 4-deep rotating lookahead (A0..A3, reload tap+4 after
//     use) so steady-state vmcnt waits ~0; B via LDS dbuf + P/Q 1-tap-ahead.
//     ONE barrier per c-step, gated by counted vmcnt(16) (A pipeline never
//     drained; in-order vm retirement proves the older GLLX landed).
//     Epilogue: accP+accQ, fused channel RMSNorm * gamma * 16 + SiLU.

typedef __attribute__((ext_vector_type(8))) short short8;
typedef __attribute__((ext_vector_type(16))) float f32x16;

#define GLL16(src, dst)                                                       \
  __builtin_amdgcn_global_load_lds(                                           \
      (const __attribute__((address_space(1))) unsigned int*)(src),           \
      (__attribute__((address_space(3))) unsigned int*)(dst), 16, 0, 0)

static __device__ __forceinline__ unsigned short f2bf(float v) {
  union { float f; unsigned u; } u;
  u.f = v;
  unsigned r = u.u + 0x7FFF + ((u.u >> 16) & 1);  // RNE
  return (unsigned short)(r >> 16);
}

// ---------------------------------------------------------------------------
// Kernel 1: fused weight prep. Grid 512 = b(16) x oq(32 o-octets), 256 thr.
// ---------------------------------------------------------------------------
__global__ __launch_bounds__(256) void wprep(
    const float* __restrict__ mod, const float* __restrict__ kmod,
    const float* __restrict__ weights, unsigned short* __restrict__ wq) {
  int blk = blockIdx.x;  // b*32 + oq
  int b = blk >> 5, oq = blk & 31;
  int t = threadIdx.x;
  int o_l = t >> 5, its = t & 31;
  int o = oq * 8 + o_l;

  float k0 = kmod[b * 2 + 0], k1 = kmod[b * 2 + 1];
  float mx = fmaxf(k0, k1);
  float e0 = expf(k0 - mx), e1 = expf(k1 - mx);
  float ai = 1.0f / (e0 + e1);
  float a0 = e0 * ai, a1 = e1 * ai;

  float wv[9][8];  // [j][e]
  float s = 0.0f;
  const float* w0 = &weights[((size_t)o * 256 + its * 8) * 9];
  const float* w1 = w0 + 589824;
#pragma unroll
  for (int e = 0; e < 8; ++e) {
    float f = mod[b * 256 + its * 8 + e] + 1.0f;
#pragma unroll
    for (int j = 0; j < 9; ++j) {
      float v = (a0 * w0[e * 9 + j] + a1 * w1[e * 9 + j]) * f;
      wv[j][e] = v;
      s = fmaf(v, v, s);
    }
  }

  __shared__ float red[8][32];
  __shared__ float scl[8];
  red[o_l][its] = s;
  __syncthreads();
  if (t < 8) {
    float tot = 0.0f;
#pragma unroll
    for (int k = 0; k < 32; ++k) tot += red[t][k];
    scl[t] = rsqrtf(fmaxf(tot, 1e-8f));
  }
  __syncthreads();
  float sc = scl[o_l];

  int c = its >> 1, io = its & 1;
  int oh = o >> 7, mf = (o >> 5) & 3;
  int lane2 = (o & 31) + io * 32;
  // chunk [tap9][oh2][mf4][lane64][e8] ush per (b,c)
  size_t cbase = ((size_t)(b * 16 + c)) * 36864 + oh * 2048 + mf * 512 + lane2 * 8;
#pragma unroll
  for (int j = 0; j < 9; ++j) {
    short8 pk;
#pragma unroll
    for (int e = 0; e < 8; ++e) pk[e] = (short)f2bf(wv[j][e] * sc);
    *(short8*)(wq + cbase + j * 4096) = pk;
  }
}

// ---------------------------------------------------------------------------
// Kernel 2: x prep -> bf16 xq [b][c][rowp66][colp66][i16], halo zeroed, plain.
// ---------------------------------------------------------------------------
__global__ __launch_bounds__(256) void xprep(
    const float* __restrict__ x, unsigned short* __restrict__ xq) {
  int blk = blockIdx.x;  // (b*16 + c)*66 + rowp
  int rowp = blk % 66;
  int bc = blk / 66;
  int b = bc >> 4, c = bc & 15;
  int t = threadIdx.x;
  size_t obase = (size_t)blk * 1056;

  if (rowp == 0 || rowp == 65) {
    for (int idx = t; idx < 1056; idx += 256) xq[obase + idx] = 0;
    return;
  }
  __shared__ __align__(16) unsigned short xs2[1056];
  int row = rowp - 1;
  for (int idx = t; idx < 1056; idx += 256) xs2[idx] = 0;
  __syncthreads();
#pragma unroll
  for (int k = 0; k < 4; ++k) {
    int idx = t + k * 256;  // 0..1023
    int il = idx >> 6, col = idx & 63;
    float v = x[(((size_t)b * 256 + c * 16 + il) * 64 + row) * 64 + col];
    xs2[(col + 1) * 16 + il] = f2bf(v);
  }
  __syncthreads();
  if (t < 132) *(short8*)(xq + obase + (size_t)t * 8) = *(const short8*)&xs2[t * 8];
}

// ---------------------------------------------------------------------------
// Kernel 3: fused conv + RMSNorm + SiLU. Grid 256 (XCD-clustered), 512 thr.
// ---------------------------------------------------------------------------
__global__ __launch_bounds__(512, 2) void conv_fused(
    const unsigned short* __restrict__ xq, const unsigned short* __restrict__ wq,
    const float* __restrict__ gamma, float* __restrict__ out) {
  __shared__ __align__(16) unsigned short xsm[2][8192];  // x dbuf, 16 KB each
  __shared__ float redl[1024];                           // [adder4][px256]
  __shared__ float invs[256];
  __shared__ float gsm[256];

  int bid = blockIdx.x;
  int xcd = bid & 7;
  int kk = bid >> 3;            // 0..31
  int b = xcd * 2 + (kk >> 4);  // 2 batches per XCD
  int rt = kk & 15;             // 4-row tile
  int r0 = rt * 4;

  int t = threadIdx.x;
  int w = t >> 6, lane = t & 63;
  int oh = w & 1, ps = w >> 1;  // wave = (oh: 128-o half, ps: row slot 0..3)
  int l31 = lane & 31, l5 = lane >> 5;

  if (t < 256) gsm[t] = gamma[t];

  // B byte offsets per tap (plain layout): + h*1024 at use
  int boffs[9];
#pragma unroll
  for (int T = 0; T < 9; ++T) {
    int kh = T / 3, kw = T % 3;
    boffs[T] = (ps + kh) * 2112 + (l31 + kw) * 32 + l5 * 16;
  }

  f32x16 accP[4][2], accQ[4][2];
#pragma unroll
  for (int mf = 0; mf < 4; ++mf)
#pragma unroll
    for (int h = 0; h < 2; ++h)
#pragma unroll
      for (int q = 0; q < 16; ++q) { accP[mf][h][q] = 0.f; accQ[mf][h][q] = 0.f; }

  // ---- macros ----
#define GLLX(cn, nb)                                                           \
  _Pragma("unroll") for (int r = 0; r < 2; ++r) {                              \
    GLL16(xq + ((size_t)((b * 16 + (cn)) * 66 + r0)) * 1056 + (r * 512 + t) * 8, \
          &xsm[nb][(r * 512 + t) * 8]);                                        \
  }

  // A: L2-direct global load of fragment (c-chunk CC, tap TT) -> 4 short8
#define AGLB(SA, CC, TT)                                                       \
  {                                                                            \
    const unsigned short* ap_ = wq + (size_t)(b * 16 + (CC)) * 36864 +         \
                                (TT) * 4096 + oh * 2048 + lane * 8;            \
    _Pragma("unroll") for (int mf = 0; mf < 4; ++mf)                           \
        SA[mf] = *(const short8*)(ap_ + mf * 512);                             \
  }

#define BDSRD(SB, T, XB)                                                       \
  {                                                                            \
    _Pragma("unroll") for (int h = 0; h < 2; ++h)                              \
        SB[h] = *(const short8*)((XB) + boffs[T] + h * 1024);                  \
  }

#define MFMA8(SA, SB, ACC)                                                     \
  {                                                                            \
    __builtin_amdgcn_s_setprio(1);                                             \
    _Pragma("unroll") for (int h = 0; h < 2; ++h)                              \
        _Pragma("unroll") for (int mf = 0; mf < 4; ++mf)                       \
            ACC[mf][h] = __builtin_amdgcn_mfma_f32_32x32x16_bf16(              \
                SA[mf], SB[h], ACC[mf][h], 0, 0, 0);                           \
    __builtin_amdgcn_s_setprio(0);                                             \
  }

#define SBAR __builtin_amdgcn_sched_barrier(0)
#define LGKM0 asm volatile("s_waitcnt lgkmcnt(0)" ::: "memory")
#define VMC(n) asm volatile("s_waitcnt vmcnt(" #n ")" ::: "memory")
#define BAR __builtin_amdgcn_s_barrier()

  short8 A0[4], A1[4], A2[4], A3[4], PB[2], QB[2];

  const char* xs0 = (const char*)xsm[0];
  const char* xs1 = (const char*)xsm[1];

  // One c-step. Entry: S0..S3 hold taps 0..3 of C. Exit: (S1,S2,S3,S0) hold
  // taps 0..3 of C+1 (set rotation by 1 per step; 9 mod 4 == 1).
  // Gate: vmcnt(16) keeps the 16 newest A-loads (next-c taps 0..3) in flight
  // while proving the older GLLX retired (in-order vm retirement).
#define STEP(C, S0, S1, S2, S3, XB, NB)                                        \
  {                                                                            \
    int CN = (C) < 15 ? (C) + 1 : 15;                                          \
    GLLX(CN, NB);                                                              \
    BDSRD(PB, 0, XB); SBAR;                                                    \
    BDSRD(QB, 1, XB); SBAR; MFMA8(S0, PB, accP); AGLB(S0, (C), 4); SBAR;       \
    BDSRD(PB, 2, XB); SBAR; MFMA8(S1, QB, accQ); AGLB(S1, (C), 5); SBAR;       \
    BDSRD(QB, 3, XB); SBAR; MFMA8(S2, PB, accP); AGLB(S2, (C), 6); SBAR;       \
    BDSRD(PB, 4, XB); SBAR; MFMA8(S3, QB, accQ); AGLB(S3, (C), 7); SBAR;       \
    BDSRD(QB, 5, XB); SBAR; MFMA8(S0, PB, accP); AGLB(S0, (C), 8); SBAR;       \
    BDSRD(PB, 6, XB); SBAR; MFMA8(S1, QB, accQ); AGLB(S1, CN, 0); SBAR;        \
    BDSRD(QB, 7, XB); SBAR; MFMA8(S2, PB, accP); AGLB(S2, CN, 1); SBAR;        \
    BDSRD(PB, 8, XB); SBAR; MFMA8(S3, QB, accQ); AGLB(S3, CN, 2); SBAR;        \
    MFMA8(S0, PB, accP); AGLB(S0, CN, 3); SBAR;                                \
    LGKM0;                                                                     \
    VMC(16);                                                                   \
    BAR;                                                                       \
    SBAR;                                                                      \
  }

  // prologue: x(0) -> buf0; preload A0..A3 = taps 0..3 of c=0
  GLLX(0, 0);
  AGLB(A0, 0, 0); AGLB(A1, 0, 1); AGLB(A2, 0, 2); AGLB(A3, 0, 3);
  VMC(16);  // 18 outstanding -> waits the 2 oldest (GLLX) to retire
  BAR;
  SBAR;

  for (int cc = 0; cc < 16; cc += 4) {
    STEP(cc + 0, A0, A1, A2, A3, xs0, 1);
    STEP(cc + 1, A1, A2, A3, A0, xs1, 0);
    STEP(cc + 2, A2, A3, A0, A1, xs0, 1);
    STEP(cc + 3, A3, A0, A1, A2, xs1, 0);
  }

  // ---- fused epilogue: accP+accQ, RMSNorm over channels + gamma*16 + SiLU ----
  // D frag: col(px) = lane&31, o-row = (q&3) + 8*(q>>2) + 4*(lane>>5)
#pragma unroll
  for (int mf = 0; mf < 4; ++mf)
#pragma unroll
    for (int h = 0; h < 2; ++h)
#pragma unroll
      for (int q = 0; q < 16; ++q) accP[mf][h][q] += accQ[mf][h][q];

#pragma unroll
  for (int h = 0; h < 2; ++h) {
    float pssum = 0.f;
#pragma unroll
    for (int mf = 0; mf < 4; ++mf)
#pragma unroll
      for (int q = 0; q < 16; ++q) {
        float v = accP[mf][h][q];
        pssum = fmaf(v, v, pssum);
      }
    int px = ps * 64 + h * 32 + l31;
    redl[(oh * 2 + l5) * 256 + px] = pssum;
  }
  __syncthreads();
  if (t < 256) {
    float ssum = redl[t] + redl[256 + t] + redl[512 + t] + redl[768 + t];
    invs[t] = 16.0f / fmaxf(sqrtf(ssum), 1e-12f);
  }
  __syncthreads();
  float iv2[2];
#pragma unroll
  for (int h = 0; h < 2; ++h) iv2[h] = invs[ps * 64 + h * 32 + l31];

#pragma unroll
  for (int mf = 0; mf < 4; ++mf)
#pragma unroll
    for (int q = 0; q < 16; ++q) {
      int o = oh * 128 + mf * 32 + (q & 3) + 8 * (q >> 2) + 4 * l5;
      float g = gsm[o];
      size_t ob = ((size_t)b * 256 + o) * 64 + (r0 + ps);
#pragma unroll
      for (int h = 0; h < 2; ++h) {
        float v = accP[mf][h][q] * iv2[h] * g;
        float sg = 1.0f / (1.0f + expf(-v));
        out[ob * 64 + h * 32 + l31] = v * sg;
      }
    }
#undef GLLX
#undef AGLB
#undef BDSRD
#undef MFMA8
#undef SBAR
#undef LGKM0
#undef VMC
#undef BAR
#undef STEP
}

extern "C" void kernel_launch(void* const* d_in, const int* in_sizes, int n_in,
                              void* d_out, int out_size, void* d_ws, size_t ws_size,
                              hipStream_t stream) {
  const float* x = (const float*)d_in[0];
  const float* mod = (const float*)d_in[1];
  const float* kmod = (const float*)d_in[2];
  const float* weights = (const float*)d_in[3];
  const float* gamma = (const float*)d_in[4];
  float* out = (float*)d_out;

  // ws layout: xq FIRST (35,684,352 B) so conv's uniform x-stage rounds may
  // overrun harmlessly into wq; wq (18,874,368 B) after. Total ~54.6 MB.
  unsigned short* xq = (unsigned short*)d_ws;
  unsigned short* wq = (unsigned short*)((char*)d_ws + 35684352);

  wprep<<<512, 256, 0, stream>>>(mod, kmod, weights, wq);
  xprep<<<16 * 16 * 66, 256, 0, stream>>>(x, xq);
  conv_fused<<<256, 512, 0, stream>>>(xq, wq, gamma, out);
}

// Round 19
// 130.595 us; speedup vs baseline: 12.8802x; 12.8802x over previous
//
#include <hip/hip_runtime.h>
#include <math.h>

// B=16, C_IN=256, C_OUT=256, H=W=64, K=3, NK=2
// weights: [2][256][256][3][3]; bank stride 589824 floats; per-o stride 2304.
//
// Pipeline (2 kernels):
//  1. prep_all (merged): blocks [0,16896) do xprep (x -> bf16 xq
//     [b][c16][rowp66][colp66][i16], halo zeros); blocks [16896,17408) do
//     wprep (combined+modulated+demod bf16 weights -> wq per (b,c16):
//     [tap9][oh2][mf4][lane64][e8]). Merged so the two memory-bound preps
//     overlap on the device (sum -> max).
//  2. conv_fused: implicit GEMM mfma_f32_32x32x16_bf16 (9 taps = 9 MFMAs/frag).
//     Grid 512 (XCD-clustered, 2 blocks/CU anti-phase), block 256 thr
//     (4 waves) = 256 o x 2 rows x 64 px; wave = (oh,ps) 128o x 64px,
//     mf4 x nf2, acc 128 (AGPR). A-fragments L2-direct with 2-tap ping-pong
//     lookahead; B via LDS dbuf (global_load_lds) + P/Q 1-tap-ahead.
//     ONE barrier per c-step gated by counted vmcnt(8) (A pipeline never
//     drained; in-order vm retirement proves the older GLLX landed).
//     Epilogue: fused channel RMSNorm * gamma * 16 + SiLU.

typedef __attribute__((ext_vector_type(8))) short short8;
typedef __attribute__((ext_vector_type(16))) float f32x16;

#define GLL16(src, dst)                                                       \
  __builtin_amdgcn_global_load_lds(                                           \
      (const __attribute__((address_space(1))) unsigned int*)(src),           \
      (__attribute__((address_space(3))) unsigned int*)(dst), 16, 0, 0)

static __device__ __forceinline__ unsigned short f2bf(float v) {
  union { float f; unsigned u; } u;
  u.f = v;
  unsigned r = u.u + 0x7FFF + ((u.u >> 16) & 1);  // RNE
  return (unsigned short)(r >> 16);
}

// ---------------------------------------------------------------------------
// Kernel 1: merged prep. Grid 17408 x 256 thr.
//   blocks [0,16896):  xprep, blk = (b*16 + c)*66 + rowp
//   blocks [16896,..): wprep, blk2 = b*32 + oq
// ---------------------------------------------------------------------------
__global__ __launch_bounds__(256) void prep_all(
    const float* __restrict__ x, const float* __restrict__ mod,
    const float* __restrict__ kmod, const float* __restrict__ weights,
    unsigned short* __restrict__ wq, unsigned short* __restrict__ xq) {
  __shared__ __align__(16) unsigned short xs2[1056];
  __shared__ float red[8][32];
  __shared__ float scl[8];
  int t = threadIdx.x;

  if (blockIdx.x < 16896) {
    // ---------------- xprep ----------------
    int blk = blockIdx.x;
    int rowp = blk % 66;
    int bc = blk / 66;
    int b = bc >> 4, c = bc & 15;
    size_t obase = (size_t)blk * 1056;

    if (rowp == 0 || rowp == 65) {
      for (int idx = t; idx < 1056; idx += 256) xq[obase + idx] = 0;
      return;
    }
    int row = rowp - 1;
    for (int idx = t; idx < 1056; idx += 256) xs2[idx] = 0;
    __syncthreads();
#pragma unroll
    for (int k = 0; k < 4; ++k) {
      int idx = t + k * 256;  // 0..1023
      int il = idx >> 6, col = idx & 63;
      float v = x[(((size_t)b * 256 + c * 16 + il) * 64 + row) * 64 + col];
      xs2[(col + 1) * 16 + il] = f2bf(v);
    }
    __syncthreads();
    if (t < 132) *(short8*)(xq + obase + (size_t)t * 8) = *(const short8*)&xs2[t * 8];
  } else {
    // ---------------- wprep ----------------
    int blk = blockIdx.x - 16896;  // b*32 + oq
    int b = blk >> 5, oq = blk & 31;
    int o_l = t >> 5, its = t & 31;
    int o = oq * 8 + o_l;

    float k0 = kmod[b * 2 + 0], k1 = kmod[b * 2 + 1];
    float mx = fmaxf(k0, k1);
    float e0 = expf(k0 - mx), e1 = expf(k1 - mx);
    float ai = 1.0f / (e0 + e1);
    float a0 = e0 * ai, a1 = e1 * ai;

    float wv[9][8];  // [j][e]
    float s = 0.0f;
    const float* w0 = &weights[((size_t)o * 256 + its * 8) * 9];
    const float* w1 = w0 + 589824;
#pragma unroll
    for (int e = 0; e < 8; ++e) {
      float f = mod[b * 256 + its * 8 + e] + 1.0f;
#pragma unroll
      for (int j = 0; j < 9; ++j) {
        float v = (a0 * w0[e * 9 + j] + a1 * w1[e * 9 + j]) * f;
        wv[j][e] = v;
        s = fmaf(v, v, s);
      }
    }

    red[o_l][its] = s;
    __syncthreads();
    if (t < 8) {
      float tot = 0.0f;
#pragma unroll
      for (int k = 0; k < 32; ++k) tot += red[t][k];
      scl[t] = rsqrtf(fmaxf(tot, 1e-8f));
    }
    __syncthreads();
    float sc = scl[o_l];

    int c = its >> 1, io = its & 1;
    int oh = o >> 7, mf = (o >> 5) & 3;
    int lane2 = (o & 31) + io * 32;
    // chunk [tap9][oh2][mf4][lane64][e8] ush per (b,c)
    size_t cbase = ((size_t)(b * 16 + c)) * 36864 + oh * 2048 + mf * 512 + lane2 * 8;
#pragma unroll
    for (int j = 0; j < 9; ++j) {
      short8 pk;
#pragma unroll
      for (int e = 0; e < 8; ++e) pk[e] = (short)f2bf(wv[j][e] * sc);
      *(short8*)(wq + cbase + j * 4096) = pk;
    }
  }
}

// ---------------------------------------------------------------------------
// Kernel 2: fused conv + RMSNorm + SiLU. Grid 512 (XCD-clustered), 256 thr.
// ---------------------------------------------------------------------------
__global__ __launch_bounds__(256, 2) void conv_fused(
    const unsigned short* __restrict__ xq, const unsigned short* __restrict__ wq,
    const float* __restrict__ gamma, float* __restrict__ out) {
  __shared__ __align__(16) unsigned short xsm[2][6144];  // x dbuf, 12 KB each
  __shared__ float redl[512];                            // [adder4][px128]
  __shared__ float invs[128];
  __shared__ float gsm[256];

  int bid = blockIdx.x;
  int xcd = bid & 7;
  int kk = bid >> 3;            // 0..63
  int b = xcd * 2 + (kk >> 5);  // 2 batches per XCD
  int rt = kk & 31;             // 2-row tile
  int r0 = rt * 2;

  int t = threadIdx.x;
  int w = t >> 6, lane = t & 63;
  int oh = w & 1, ps = w >> 1;  // wave = (oh: 128-o half, ps: row slot 0..1)
  int l31 = lane & 31, l5 = lane >> 5;

  gsm[t] = gamma[t];

  // B byte offsets per tap (plain layout): + h*1024 at use
  int boffs[9];
#pragma unroll
  for (int T = 0; T < 9; ++T) {
    int kh = T / 3, kw = T % 3;
    boffs[T] = (ps + kh) * 2112 + (l31 + kw) * 32 + l5 * 16;
  }

  f32x16 acc[4][2];
#pragma unroll
  for (int mf = 0; mf < 4; ++mf)
#pragma unroll
    for (int h = 0; h < 2; ++h)
#pragma unroll
      for (int q = 0; q < 16; ++q) acc[mf][h][q] = 0.f;

  // ---- macros ----
  // x tile: rowp r0..r0+3 needs 4224 ush; stage 3 uniform rounds = 6144 ush
  // (overrun into next rows / wq is harmless: xq placed first in ws).
#define GLLX(cn, nb)                                                           \
  _Pragma("unroll") for (int r = 0; r < 3; ++r) {                              \
    GLL16(xq + ((size_t)((b * 16 + (cn)) * 66 + r0)) * 1056 + (r * 256 + t) * 8, \
          &xsm[nb][(r * 256 + t) * 8]);                                        \
  }

  // A: L2-direct global load of fragment (c-chunk CC, tap TT) -> 4 short8
#define AGLB(SA, CC, TT)                                                       \
  {                                                                            \
    const unsigned short* ap_ = wq + (size_t)(b * 16 + (CC)) * 36864 +         \
                                (TT) * 4096 + oh * 2048 + lane * 8;            \
    _Pragma("unroll") for (int mf = 0; mf < 4; ++mf)                           \
        SA[mf] = *(const short8*)(ap_ + mf * 512);                             \
  }

#define BDSRD(SB, T, XB)                                                       \
  {                                                                            \
    _Pragma("unroll") for (int h = 0; h < 2; ++h)                              \
        SB[h] = *(const short8*)((XB) + boffs[T] + h * 1024);                  \
  }

#define MFMA8(SA, SB)                                                          \
  {                                                                            \
    __builtin_amdgcn_s_setprio(1);                                             \
    _Pragma("unroll") for (int h = 0; h < 2; ++h)                              \
        _Pragma("unroll") for (int mf = 0; mf < 4; ++mf)                       \
            acc[mf][h] = __builtin_amdgcn_mfma_f32_32x32x16_bf16(              \
                SA[mf], SB[h], acc[mf][h], 0, 0, 0);                           \
    __builtin_amdgcn_s_setprio(0);                                             \
  }

#define SBAR __builtin_amdgcn_sched_barrier(0)
#define LGKM0 asm volatile("s_waitcnt lgkmcnt(0)" ::: "memory")
#define VMC(n) asm volatile("s_waitcnt vmcnt(" #n ")" ::: "memory")
#define BAR __builtin_amdgcn_s_barrier()

  short8 PA[4], QA[4], PB[2], QB[2];

  const char* xs0 = (const char*)xsm[0];
  const char* xs1 = (const char*)xsm[1];

  // One c-step (R17-proven). Entry: A0=tap0(C), A1=tap1(C).
  // Exit: A1=tap0(C+1), A0=tap1(C+1)  (caller swaps args each step).
#define STEP(C, A0, A1, XB, NB)                                                \
  {                                                                            \
    int CN = (C) < 15 ? (C) + 1 : 15;                                          \
    GLLX(CN, NB);                                                              \
    BDSRD(PB, 0, XB); SBAR;                                                    \
    BDSRD(QB, 1, XB); SBAR; MFMA8(A0, PB); AGLB(A0, (C), 2); SBAR;             \
    BDSRD(PB, 2, XB); SBAR; MFMA8(A1, QB); AGLB(A1, (C), 3); SBAR;             \
    BDSRD(QB, 3, XB); SBAR; MFMA8(A0, PB); AGLB(A0, (C), 4); SBAR;             \
    BDSRD(PB, 4, XB); SBAR; MFMA8(A1, QB); AGLB(A1, (C), 5); SBAR;             \
    BDSRD(QB, 5, XB); SBAR; MFMA8(A0, PB); AGLB(A0, (C), 6); SBAR;             \
    BDSRD(PB, 6, XB); SBAR; MFMA8(A1, QB); AGLB(A1, (C), 7); SBAR;             \
    BDSRD(QB, 7, XB); SBAR; MFMA8(A0, PB); AGLB(A0, (C), 8); SBAR;             \
    BDSRD(PB, 8, XB); SBAR; MFMA8(A1, QB); AGLB(A1, CN, 0); SBAR;              \
    MFMA8(A0, PB); AGLB(A0, CN, 1); SBAR;                                      \
    LGKM0;                                                                     \
    VMC(8);                                                                    \
    BAR;                                                                       \
    SBAR;                                                                      \
  }

  // prologue: x(0) -> buf0; preload A(0,0)->PA, A(0,1)->QA
  GLLX(0, 0);
  AGLB(PA, 0, 0);
  AGLB(QA, 0, 1);
  VMC(8);  // 11 outstanding -> retires the 3 GLLX; PA/QA stay in flight
  BAR;
  SBAR;

  for (int cc = 0; cc < 16; cc += 2) {
    STEP(cc, PA, QA, xs0, 1);
    STEP(cc + 1, QA, PA, xs1, 0);
  }

  // ---- fused epilogue: RMSNorm over channels + gamma*16 + SiLU ----
  // D frag: col(px) = lane&31, o-row = (q&3) + 8*(q>>2) + 4*(lane>>5)
#pragma unroll
  for (int h = 0; h < 2; ++h) {
    float pssum = 0.f;
#pragma unroll
    for (int mf = 0; mf < 4; ++mf)
#pragma unroll
      for (int q = 0; q < 16; ++q) {
        float v = acc[mf][h][q];
        pssum = fmaf(v, v, pssum);
      }
    int px = ps * 64 + h * 32 + l31;  // 0..127
    redl[(oh * 2 + l5) * 128 + px] = pssum;
  }
  __syncthreads();
  if (t < 128) {
    float ssum = redl[t] + redl[128 + t] + redl[256 + t] + redl[384 + t];
    invs[t] = 16.0f / fmaxf(sqrtf(ssum), 1e-12f);
  }
  __syncthreads();
  float iv2[2];
#pragma unroll
  for (int h = 0; h < 2; ++h) iv2[h] = invs[ps * 64 + h * 32 + l31];

#pragma unroll
  for (int mf = 0; mf < 4; ++mf)
#pragma unroll
    for (int q = 0; q < 16; ++q) {
      int o = oh * 128 + mf * 32 + (q & 3) + 8 * (q >> 2) + 4 * l5;
      float g = gsm[o];
      size_t ob = ((size_t)b * 256 + o) * 64 + (r0 + ps);
#pragma unroll
      for (int h = 0; h < 2; ++h) {
        float v = acc[mf][h][q] * iv2[h] * g;
        float sg = 1.0f / (1.0f + expf(-v));
        out[ob * 64 + h * 32 + l31] = v * sg;
      }
    }
#undef GLLX
#undef AGLB
#undef BDSRD
#undef MFMA8
#undef SBAR
#undef LGKM0
#undef VMC
#undef BAR
#undef STEP
}

extern "C" void kernel_launch(void* const* d_in, const int* in_sizes, int n_in,
                              void* d_out, int out_size, void* d_ws, size_t ws_size,
                              hipStream_t stream) {
  const float* x = (const float*)d_in[0];
  const float* mod = (const float*)d_in[1];
  const float* kmod = (const float*)d_in[2];
  const float* weights = (const float*)d_in[3];
  const float* gamma = (const float*)d_in[4];
  float* out = (float*)d_out;

  // ws layout: xq FIRST (35,684,352 B) so conv's uniform x-stage rounds may
  // overrun harmlessly into wq; wq (18,874,368 B) after. Total ~54.6 MB.
  unsigned short* xq = (unsigned short*)d_ws;
  unsigned short* wq = (unsigned short*)((char*)d_ws + 35684352);

  prep_all<<<16896 + 512, 256, 0, stream>>>(x, mod, kmod, weights, wq, xq);
  conv_fused<<<512, 256, 0, stream>>>(xq, wq, gamma, out);
}

// Round 20
// 122.524 us; speedup vs baseline: 13.7286x; 1.0659x over previous
//
#include <hip/hip_runtime.h>
#include <math.h>

// B=16, C_IN=256, C_OUT=256, H=W=64, K=3, NK=2
// weights: [2][256][256][3][3]; bank stride 589824 floats; per-o stride 2304.
//
// Pipeline (3 kernels):
//  1. wprep: combined+modulated+demod bf16 weights -> wq per (b,c16):
//     [tap9][oh2][mf4][lane64][e8] (36864 ush). Read DIRECTLY from L2 by conv.
//  2. xprep: x -> bf16 xq [b][c16][rowp66][colp66][i16], halo zeros, plain.
//  3. conv_fused: implicit GEMM mfma_f32_32x32x16_bf16 (9 taps = 9 MFMAs/frag).
//     Grid 512 (XCD-clustered, 2 anti-phase blocks/CU), block 256 thr
//     (4 waves) = 256 o x 2 rows x 64 px; wave = (oh,ps) 128o x 64px,
//     mf4 x nf2, acc 128 (AGPR). A-fragments L2-direct with 3-DEEP rotating
//     lookahead (S0/S1/S2; reload tap+3 after use; 9%3==0 -> identity
//     rotation, plain c-loop). B via LDS dbuf + PB/QB 1-tap-ahead.
//     ONE barrier per c-step gated by counted vmcnt(12) (the 12 next-c
//     A-loads never drain; tap-8's use-wait already implies vmcnt<=12).
//     Epilogue: fused channel RMSNorm * gamma * 16 + SiLU.

typedef __attribute__((ext_vector_type(8))) short short8;
typedef __attribute__((ext_vector_type(16))) float f32x16;

#define GLL16(src, dst)                                                       \
  __builtin_amdgcn_global_load_lds(                                           \
      (const __attribute__((address_space(1))) unsigned int*)(src),           \
      (__attribute__((address_space(3))) unsigned int*)(dst), 16, 0, 0)

static __device__ __forceinline__ unsigned short f2bf(float v) {
  union { float f; unsigned u; } u;
  u.f = v;
  unsigned r = u.u + 0x7FFF + ((u.u >> 16) & 1);  // RNE
  return (unsigned short)(r >> 16);
}

// ---------------------------------------------------------------------------
// Kernel 1: fused weight prep. Grid 512 = b(16) x oq(32 o-octets), 256 thr.
// ---------------------------------------------------------------------------
__global__ __launch_bounds__(256) void wprep(
    const float* __restrict__ mod, const float* __restrict__ kmod,
    const float* __restrict__ weights, unsigned short* __restrict__ wq) {
  int blk = blockIdx.x;  // b*32 + oq
  int b = blk >> 5, oq = blk & 31;
  int t = threadIdx.x;
  int o_l = t >> 5, its = t & 31;
  int o = oq * 8 + o_l;

  float k0 = kmod[b * 2 + 0], k1 = kmod[b * 2 + 1];
  float mx = fmaxf(k0, k1);
  float e0 = expf(k0 - mx), e1 = expf(k1 - mx);
  float ai = 1.0f / (e0 + e1);
  float a0 = e0 * ai, a1 = e1 * ai;

  float wv[9][8];  // [j][e]
  float s = 0.0f;
  const float* w0 = &weights[((size_t)o * 256 + its * 8) * 9];
  const float* w1 = w0 + 589824;
#pragma unroll
  for (int e = 0; e < 8; ++e) {
    float f = mod[b * 256 + its * 8 + e] + 1.0f;
#pragma unroll
    for (int j = 0; j < 9; ++j) {
      float v = (a0 * w0[e * 9 + j] + a1 * w1[e * 9 + j]) * f;
      wv[j][e] = v;
      s = fmaf(v, v, s);
    }
  }

  __shared__ float red[8][32];
  __shared__ float scl[8];
  red[o_l][its] = s;
  __syncthreads();
  if (t < 8) {
    float tot = 0.0f;
#pragma unroll
    for (int k = 0; k < 32; ++k) tot += red[t][k];
    scl[t] = rsqrtf(fmaxf(tot, 1e-8f));
  }
  __syncthreads();
  float sc = scl[o_l];

  int c = its >> 1, io = its & 1;
  int oh = o >> 7, mf = (o >> 5) & 3;
  int lane2 = (o & 31) + io * 32;
  // chunk [tap9][oh2][mf4][lane64][e8] ush per (b,c)
  size_t cbase = ((size_t)(b * 16 + c)) * 36864 + oh * 2048 + mf * 512 + lane2 * 8;
#pragma unroll
  for (int j = 0; j < 9; ++j) {
    short8 pk;
#pragma unroll
    for (int e = 0; e < 8; ++e) pk[e] = (short)f2bf(wv[j][e] * sc);
    *(short8*)(wq + cbase + j * 4096) = pk;
  }
}

// ---------------------------------------------------------------------------
// Kernel 2: x prep -> bf16 xq [b][c][rowp66][colp66][i16], halo zeroed, plain.
// ---------------------------------------------------------------------------
__global__ __launch_bounds__(256) void xprep(
    const float* __restrict__ x, unsigned short* __restrict__ xq) {
  int blk = blockIdx.x;  // (b*16 + c)*66 + rowp
  int rowp = blk % 66;
  int bc = blk / 66;
  int b = bc >> 4, c = bc & 15;
  int t = threadIdx.x;
  size_t obase = (size_t)blk * 1056;

  if (rowp == 0 || rowp == 65) {
    for (int idx = t; idx < 1056; idx += 256) xq[obase + idx] = 0;
    return;
  }
  __shared__ __align__(16) unsigned short xs2[1056];
  int row = rowp - 1;
  for (int idx = t; idx < 1056; idx += 256) xs2[idx] = 0;
  __syncthreads();
#pragma unroll
  for (int k = 0; k < 4; ++k) {
    int idx = t + k * 256;  // 0..1023
    int il = idx >> 6, col = idx & 63;
    float v = x[(((size_t)b * 256 + c * 16 + il) * 64 + row) * 64 + col];
    xs2[(col + 1) * 16 + il] = f2bf(v);
  }
  __syncthreads();
  if (t < 132) *(short8*)(xq + obase + (size_t)t * 8) = *(const short8*)&xs2[t * 8];
}

// ---------------------------------------------------------------------------
// Kernel 3: fused conv + RMSNorm + SiLU. Grid 512 (XCD-clustered), 256 thr.
// ---------------------------------------------------------------------------
__global__ __launch_bounds__(256, 2) void conv_fused(
    const unsigned short* __restrict__ xq, const unsigned short* __restrict__ wq,
    const float* __restrict__ gamma, float* __restrict__ out) {
  __shared__ __align__(16) unsigned short xsm[2][6144];  // x dbuf, 12 KB each
  __shared__ float redl[512];                            // [adder4][px128]
  __shared__ float invs[128];
  __shared__ float gsm[256];

  int bid = blockIdx.x;
  int xcd = bid & 7;
  int kk = bid >> 3;            // 0..63
  int b = xcd * 2 + (kk >> 5);  // 2 batches per XCD
  int rt = kk & 31;             // 2-row tile
  int r0 = rt * 2;

  int t = threadIdx.x;
  int w = t >> 6, lane = t & 63;
  int oh = w & 1, ps = w >> 1;  // wave = (oh: 128-o half, ps: row slot 0..1)
  int l31 = lane & 31, l5 = lane >> 5;

  gsm[t] = gamma[t];

  // B byte offsets per tap (plain layout): + h*1024 at use
  int boffs[9];
#pragma unroll
  for (int T = 0; T < 9; ++T) {
    int kh = T / 3, kw = T % 3;
    boffs[T] = (ps + kh) * 2112 + (l31 + kw) * 32 + l5 * 16;
  }

  f32x16 acc[4][2];
#pragma unroll
  for (int mf = 0; mf < 4; ++mf)
#pragma unroll
    for (int h = 0; h < 2; ++h)
#pragma unroll
      for (int q = 0; q < 16; ++q) acc[mf][h][q] = 0.f;

  // ---- macros ----
  // x tile: rowp r0..r0+3 needs 4224 ush; stage 3 uniform rounds = 6144 ush
  // (overrun into next rows / wq is harmless: xq placed first in ws).
#define GLLX(cn, nb)                                                           \
  _Pragma("unroll") for (int r = 0; r < 3; ++r) {                              \
    GLL16(xq + ((size_t)((b * 16 + (cn)) * 66 + r0)) * 1056 + (r * 256 + t) * 8, \
          &xsm[nb][(r * 256 + t) * 8]);                                        \
  }

  // A: L2-direct global load of fragment (c-chunk CC, tap TT) -> 4 short8
#define AGLB(SA, CC, TT)                                                       \
  {                                                                            \
    const unsigned short* ap_ = wq + (size_t)(b * 16 + (CC)) * 36864 +         \
                                (TT) * 4096 + oh * 2048 + lane * 8;            \
    _Pragma("unroll") for (int mf = 0; mf < 4; ++mf)                           \
        SA[mf] = *(const short8*)(ap_ + mf * 512);                             \
  }

#define BDSRD(SB, T, XB)                                                       \
  {                                                                            \
    _Pragma("unroll") for (int h = 0; h < 2; ++h)                              \
        SB[h] = *(const short8*)((XB) + boffs[T] + h * 1024);                  \
  }

#define MFMA8(SA, SB)                                                          \
  {                                                                            \
    __builtin_amdgcn_s_setprio(1);                                             \
    _Pragma("unroll") for (int h = 0; h < 2; ++h)                              \
        _Pragma("unroll") for (int mf = 0; mf < 4; ++mf)                       \
            acc[mf][h] = __builtin_amdgcn_mfma_f32_32x32x16_bf16(              \
                SA[mf], SB[h], acc[mf][h], 0, 0, 0);                           \
    __builtin_amdgcn_s_setprio(0);                                             \
  }

#define SBAR __builtin_amdgcn_sched_barrier(0)
#define LGKM0 asm volatile("s_waitcnt lgkmcnt(0)" ::: "memory")
#define VMC(n) asm volatile("s_waitcnt vmcnt(" #n ")" ::: "memory")
#define BAR __builtin_amdgcn_s_barrier()

  short8 S0[4], S1[4], S2[4], PB[2], QB[2];

  const char* xs0 = (const char*)xsm[0];
  const char* xs1 = (const char*)xsm[1];

  // prologue: x(0) -> buf0; preload A-sets with taps 0..2 of c=0
  GLLX(0, 0);
  AGLB(S0, 0, 0);
  AGLB(S1, 0, 1);
  AGLB(S2, 0, 2);
  VMC(12);  // 15 outstanding -> retires the 3 GLLX; S0..S2 stay in flight
  BAR;
  SBAR;

  for (int c = 0; c < 16; ++c) {
    const char* XB = (c & 1) ? xs1 : xs0;
    int NB = (c & 1) ^ 1;
    int CN = c < 15 ? c + 1 : 15;
    GLLX(CN, NB);
    BDSRD(PB, 0, XB); SBAR;
    BDSRD(QB, 1, XB); SBAR; MFMA8(S0, PB); AGLB(S0, c, 3); SBAR;
    BDSRD(PB, 2, XB); SBAR; MFMA8(S1, QB); AGLB(S1, c, 4); SBAR;
    BDSRD(QB, 3, XB); SBAR; MFMA8(S2, PB); AGLB(S2, c, 5); SBAR;
    BDSRD(PB, 4, XB); SBAR; MFMA8(S0, QB); AGLB(S0, c, 6); SBAR;
    BDSRD(QB, 5, XB); SBAR; MFMA8(S1, PB); AGLB(S1, c, 7); SBAR;
    BDSRD(PB, 6, XB); SBAR; MFMA8(S2, QB); AGLB(S2, c, 8); SBAR;
    BDSRD(QB, 7, XB); SBAR; MFMA8(S0, PB); AGLB(S0, CN, 0); SBAR;
    BDSRD(PB, 8, XB); SBAR; MFMA8(S1, QB); AGLB(S1, CN, 1); SBAR;
    MFMA8(S2, PB); AGLB(S2, CN, 2); SBAR;
    LGKM0;   // my LDS reads of XB done
    VMC(12); // keep the 12 next-c A-loads in flight; GLLX(CN) provably retired
    BAR;     // buffer swap point
    SBAR;
  }

  // ---- fused epilogue: RMSNorm over channels + gamma*16 + SiLU ----
  // D frag: col(px) = lane&31, o-row = (q&3) + 8*(q>>2) + 4*(lane>>5)
#pragma unroll
  for (int h = 0; h < 2; ++h) {
    float pssum = 0.f;
#pragma unroll
    for (int mf = 0; mf < 4; ++mf)
#pragma unroll
      for (int q = 0; q < 16; ++q) {
        float v = acc[mf][h][q];
        pssum = fmaf(v, v, pssum);
      }
    int px = ps * 64 + h * 32 + l31;  // 0..127
    redl[(oh * 2 + l5) * 128 + px] = pssum;
  }
  __syncthreads();
  if (t < 128) {
    float ssum = redl[t] + redl[128 + t] + redl[256 + t] + redl[384 + t];
    invs[t] = 16.0f / fmaxf(sqrtf(ssum), 1e-12f);
  }
  __syncthreads();
  float iv2[2];
#pragma unroll
  for (int h = 0; h < 2; ++h) iv2[h] = invs[ps * 64 + h * 32 + l31];

#pragma unroll
  for (int mf = 0; mf < 4; ++mf)
#pragma unroll
    for (int q = 0; q < 16; ++q) {
      int o = oh * 128 + mf * 32 + (q & 3) + 8 * (q >> 2) + 4 * l5;
      float g = gsm[o];
      size_t ob = ((size_t)b * 256 + o) * 64 + (r0 + ps);
#pragma unroll
      for (int h = 0; h < 2; ++h) {
        float v = acc[mf][h][q] * iv2[h] * g;
        float sg = 1.0f / (1.0f + expf(-v));
        out[ob * 64 + h * 32 + l31] = v * sg;
      }
    }
#undef GLLX
#undef AGLB
#undef BDSRD
#undef MFMA8
#undef SBAR
#undef LGKM0
#undef VMC
#undef BAR
}

extern "C" void kernel_launch(void* const* d_in, const int* in_sizes, int n_in,
                              void* d_out, int out_size, void* d_ws, size_t ws_size,
                              hipStream_t stream) {
  const float* x = (const float*)d_in[0];
  const float* mod = (const float*)d_in[1];
  const float* kmod = (const float*)d_in[2];
  const float* weights = (const float*)d_in[3];
  const float* gamma = (const float*)d_in[4];
  float* out = (float*)d_out;

  // ws layout: xq FIRST (35,684,352 B) so conv's uniform x-stage rounds may
  // overrun harmlessly into wq; wq (18,874,368 B) after. Total ~54.6 MB.
  unsigned short* xq = (unsigned short*)d_ws;
  unsigned short* wq = (unsigned short*)((char*)d_ws + 35684352);

  wprep<<<512, 256, 0, stream>>>(mod, kmod, weights, wq);
  xprep<<<16 * 16 * 66, 256, 0, stream>>>(x, xq);
  conv_fused<<<512, 256, 0, stream>>>(xq, wq, gamma, out);
}